// Round 3
// baseline (40.196 us; speedup 1.0000x reference)
//
#include <hip/hip_runtime.h>
#include <hip/hip_bf16.h>
#include <float.h>

#define NGROUPS 128
#define SLOT    512   // fixed per-group slot (group sizes ~128±12; 512 is 30+ sigma)

// ws layout: [0,512B) counts (int[128]) | [512B, 512B + 128*512*16B) gx float4 slots

// ---- bucket: one block per group; scan idx, compact members' coords to slot ----
__global__ __launch_bounds__(256) void kde_bucket(
        const int* __restrict__ idx,
        const float* __restrict__ x,
        int M,
        int* __restrict__ counts,
        float4* __restrict__ gx) {
    __shared__ int lc;
    if (threadIdx.x == 0) lc = 0;
    __syncthreads();
    const int g = blockIdx.x;
    float4* __restrict__ slot = gx + (size_t)g * SLOT;
    for (int i = threadIdx.x; i < M; i += 256) {
        if (idx[i] == g) {
            int p = atomicAdd(&lc, 1);
            if (p < SLOT) {
                float4 v;
                v.x = x[3 * i + 0];
                v.y = x[3 * i + 1];
                v.z = x[3 * i + 2];
                v.w = 0.0f;
                slot[p] = v;
            }
        }
    }
    __syncthreads();
    if (threadIdx.x == 0) counts[g] = (lc < SLOT) ? lc : SLOT;
}

// ---- select: one 64-lane wave per point ----
// Per lane: sorted ascending top-16 of its strided candidate slice (static
// register chain). Then K cooperative pops: wave-min of heads via DPP
// (VALU pipe), ballot -> leader pops its head. Exact for any c: one lane can
// contribute at most K<=16 values to the global top-K.

#define DPP_MIN_STEP(v, CTRL)                                                  \
    v = fminf(v, __int_as_float(__builtin_amdgcn_update_dpp(                   \
            0x7f7fffff /*FLT_MAX bits*/, __float_as_int(v), CTRL, 0xf, 0xf,    \
            false)))

__global__ __launch_bounds__(256) void kde_select(
        const float* __restrict__ x,
        const int* __restrict__ idx,
        const float4* __restrict__ gx,
        const int* __restrict__ counts,
        const int* __restrict__ Kptr,
        int M,
        float* __restrict__ out) {
    const int wid  = (blockIdx.x << 2) | (threadIdx.x >> 6);  // point id
    const int lane = threadIdx.x & 63;
    if (wid >= M) return;

    const int g = idx[wid];
    const int c = counts[g];
    const int K = Kptr[0];
    const float4* __restrict__ slot = gx + (size_t)g * SLOT;

    const float xm = x[3 * wid + 0];
    const float ym = x[3 * wid + 1];
    const float zm = x[3 * wid + 2];

    float s0 = FLT_MAX, s1 = FLT_MAX, s2 = FLT_MAX, s3 = FLT_MAX;
    float s4 = FLT_MAX, s5 = FLT_MAX, s6 = FLT_MAX, s7 = FLT_MAX;
    float s8 = FLT_MAX, s9 = FLT_MAX, s10 = FLT_MAX, s11 = FLT_MAX;
    float s12 = FLT_MAX, s13 = FLT_MAX, s14 = FLT_MAX, s15 = FLT_MAX;

#define KNN_INSERT(dval)                                                      \
    do {                                                                      \
        float v_ = (dval);                                                    \
        if (v_ < s15) {                                                       \
            float tt_;                                                        \
            if (v_ < s0)  { tt_ = s0;  s0  = v_; v_ = tt_; }                  \
            if (v_ < s1)  { tt_ = s1;  s1  = v_; v_ = tt_; }                  \
            if (v_ < s2)  { tt_ = s2;  s2  = v_; v_ = tt_; }                  \
            if (v_ < s3)  { tt_ = s3;  s3  = v_; v_ = tt_; }                  \
            if (v_ < s4)  { tt_ = s4;  s4  = v_; v_ = tt_; }                  \
            if (v_ < s5)  { tt_ = s5;  s5  = v_; v_ = tt_; }                  \
            if (v_ < s6)  { tt_ = s6;  s6  = v_; v_ = tt_; }                  \
            if (v_ < s7)  { tt_ = s7;  s7  = v_; v_ = tt_; }                  \
            if (v_ < s8)  { tt_ = s8;  s8  = v_; v_ = tt_; }                  \
            if (v_ < s9)  { tt_ = s9;  s9  = v_; v_ = tt_; }                  \
            if (v_ < s10) { tt_ = s10; s10 = v_; v_ = tt_; }                  \
            if (v_ < s11) { tt_ = s11; s11 = v_; v_ = tt_; }                  \
            if (v_ < s12) { tt_ = s12; s12 = v_; v_ = tt_; }                  \
            if (v_ < s13) { tt_ = s13; s13 = v_; v_ = tt_; }                  \
            if (v_ < s14) { tt_ = s14; s14 = v_; v_ = tt_; }                  \
            s15 = v_;                                                         \
        }                                                                     \
    } while (0)

    for (int j = lane; j < c; j += 64) {
        const float4 v = slot[j];
        const float dx = v.x - xm;
        const float dy = v.y - ym;
        const float dz = v.z - zm;
        const float d2 = dx * dx + dy * dy + dz * dz;
        KNN_INSERT(d2);
    }
#undef KNN_INSERT

    // K cooperative pops; after the loop `ans` is the K-th smallest d^2
    // (multiset includes the self-distance 0, matching the reference).
    float ans = FLT_MAX;
    for (int it = 0; it < K; ++it) {
        float v = s0;
        DPP_MIN_STEP(v, 0x111);  // row_shr:1
        DPP_MIN_STEP(v, 0x112);  // row_shr:2
        DPP_MIN_STEP(v, 0x114);  // row_shr:4
        DPP_MIN_STEP(v, 0x118);  // row_shr:8
        DPP_MIN_STEP(v, 0x142);  // row_bcast:15
        DPP_MIN_STEP(v, 0x143);  // row_bcast:31
        const float m = __int_as_float(
            __builtin_amdgcn_readlane(__float_as_int(v), 63));
        ans = m;
        const unsigned long long bal = __ballot(s0 == m);
        const int leader = (int)__ffsll(bal) - 1;
        if (lane == leader) {  // pop exactly one instance (handles ties)
            s0 = s1; s1 = s2; s2 = s3; s3 = s4; s4 = s5; s5 = s6; s6 = s7;
            s7 = s8; s8 = s9; s9 = s10; s10 = s11; s11 = s12; s12 = s13;
            s13 = s14; s14 = s15; s15 = FLT_MAX;
        }
    }

    if (lane == 0) {
        // dim = NI-1 = 2: volume = pi*r^2 = pi*ans (ans is squared distance).
        float p = (c < K) ? (1.0f / (float)c)
                          : (3.14159265358979323846f * ans / (float)(K - 1));
        out[wid] = p;
    }
}

extern "C" void kernel_launch(void* const* d_in, const int* in_sizes, int n_in,
                              void* d_out, int out_size, void* d_ws, size_t ws_size,
                              hipStream_t stream) {
    const float* x   = (const float*)d_in[0];
    const int*   idx = (const int*)d_in[1];
    const int*   Kp  = (const int*)d_in[2];
    float* out = (float*)d_out;

    const int M = in_sizes[1];  // 16384

    int*    counts = (int*)d_ws;
    float4* gx     = (float4*)((char*)d_ws + 512);

    kde_bucket<<<NGROUPS, 256, 0, stream>>>(idx, x, M, counts, gx);

    const int blocks = (M + 3) / 4;  // 4 waves (points) per 256-thread block
    kde_select<<<blocks, 256, 0, stream>>>(x, idx, gx, counts, Kp, M, out);
}